// Round 5
// baseline (276.366 us; speedup 1.0000x reference)
//
#include <hip/hip_runtime.h>
#include <hip/hip_bf16.h>
#include <math.h>

// Problem: B=16, C=512, N=H*W=4096, K=32
#define BB 16
#define CC 512
#define NN 4096
#define KK 32

typedef __attribute__((ext_vector_type(8))) short short8;
typedef __attribute__((ext_vector_type(4))) short short4v;
typedef __attribute__((ext_vector_type(4))) float float4v;
typedef __attribute__((ext_vector_type(4))) unsigned int uint4v;

static __device__ __forceinline__ unsigned short f2bf(float f) {
  unsigned u = __float_as_uint(f);
  u += 0x7FFF + ((u >> 16) & 1);  // RNE
  return (unsigned short)(u >> 16);
}

static __device__ __forceinline__ short8 cat8(short4v a, short4v b) {
  short8 r;
  r[0] = a[0]; r[1] = a[1]; r[2] = a[2]; r[3] = a[3];
  r[4] = b[0]; r[5] = b[1]; r[6] = b[2]; r[7] = b[3];
  return r;
}

// ws layout (bytes):
//   [0,128)        c2     (32 fp32)
//   [128,32896)    cwP    (32 k x 512 c) bf16, c-PERMUTED within 32-blocks
//   [32896,34944)  asum   (B*K fp32)
//   new path (ws >= ~139 MB):
//   [35072, +4MB)          x2p   : 16 b x 16 slabs x 4096 n fp32 partial x^2
//   [+4MB, +4.25MB)        x2f   : 16 b x 4096 n fp32 exact x^2
//   [+4.25MB, +71.3MB)     x_t   : bf16 x, tiled [b][chunk64][sub32][c][n32]
//   [+71.3MB, +138.4MB)    partials: 1024 x (32 k x 512 c) fp32
//   legacy fallback: partials at 35072 (512 tiles).
//
// v6 rationale: r0-r4 showed fused is bound by the strided fp32 x read
// (8 scattered 128B segments / wave-instr at 16KB stride) + the cvt/x2
// chains, not by occupancy (r1/r2), L3 policy (r3), or in-block overlap
// (r4: reg prefetch spilled -> 209MB scratch writes). So: passA streams x
// coalesced once, emits bf16 tiles in EXACT fused staging order + exact
// fp32 x^2; fused staging becomes 8 coalesced 16B loads/thread.

// ---------------- K0: prep (unchanged) ----------------
__global__ __launch_bounds__(256) void prep_kernel(
    const float* __restrict__ cw, unsigned short* __restrict__ cwP,
    float* __restrict__ c2, float* __restrict__ asum) {
  int gid = blockIdx.x * 256 + threadIdx.x;  // 16384 threads = K*C
  if (gid < BB * KK) asum[gid] = 0.f;
  {
    int k = gid >> 9;
    int cc = gid & 511;
    int cs = cc & ~31;
    int w5 = cc & 31;
    int q = w5 >> 3, j = w5 & 7;
    int src_c = cs + 2 * q + (j & 1) + ((j >> 1) << 3);
    cwP[gid] = f2bf(cw[k * CC + src_c]);
  }
  __shared__ float c2p[KK][8];
  if (blockIdx.x == 0) {
    int k = threadIdx.x >> 3, j = threadIdx.x & 7;
    const float* row = cw + k * CC + j * 64;
    float s = 0.f;
    for (int i = 0; i < 64; ++i) s = fmaf(row[i], row[i], s);
    c2p[k][j] = s;
    __syncthreads();
    if (threadIdx.x < KK) {
      float t = 0.f;
      for (int j2 = 0; j2 < 8; ++j2) t += c2p[threadIdx.x][j2];
      c2[threadIdx.x] = t;
    }
  }
}

// ---------------- K0b: passA — stream x -> bf16 tiles + x2 partials -----
// grid 256 = 16 b x 16 slabs (32 c each). Fully coalesced reads along n
// (1KB/wave/instr). Writes x_t[b][chunk][sub][c][n32] bf16 + x2p fp32.
__global__ __launch_bounds__(256) void passA_kernel(
    const float* __restrict__ x, unsigned short* __restrict__ xt,
    float* __restrict__ x2p) {
  const int b = blockIdx.x >> 4;
  const int slab = blockIdx.x & 15;
  const int t = threadIdx.x;
  const float* xb = x + (size_t)b * CC * NN + (size_t)slab * 32 * NN;

  float4v x2a[4];
#pragma unroll
  for (int i = 0; i < 4; ++i) x2a[i] = (float4v){0.f, 0.f, 0.f, 0.f};

  for (int cl = 0; cl < 32; ++cl) {
    const float* row = xb + (size_t)cl * NN;
    const int c = slab * 32 + cl;
#pragma unroll
    for (int i = 0; i < 4; ++i) {
      const int n0 = i * 1024 + t * 4;
      float4v v = *(const float4v*)(row + n0);
      x2a[i].x = fmaf(v.x, v.x, x2a[i].x);
      x2a[i].y = fmaf(v.y, v.y, x2a[i].y);
      x2a[i].z = fmaf(v.z, v.z, x2a[i].z);
      x2a[i].w = fmaf(v.w, v.w, x2a[i].w);
      unsigned p0 = (unsigned)f2bf(v.x) | ((unsigned)f2bf(v.y) << 16);
      unsigned p1 = (unsigned)f2bf(v.z) | ((unsigned)f2bf(v.w) << 16);
      const int chunk = n0 >> 6;
      const int sub = (n0 >> 5) & 1;
      const int n32 = n0 & 31;
      size_t off = ((((size_t)(b * 64 + chunk) * 2 + sub) * CC + c) * 32 + n32);
      *(uint2*)&xt[off] = make_uint2(p0, p1);
    }
  }
#pragma unroll
  for (int i = 0; i < 4; ++i)
    *(float4v*)&x2p[((size_t)(b * 16 + slab)) * NN + i * 1024 + t * 4] = x2a[i];
}

// ---------------- K0c: x2sum — fold 16 slab partials ----------------
__global__ __launch_bounds__(256) void x2sum_kernel(
    const float* __restrict__ x2p, float* __restrict__ x2f) {
  int g = blockIdx.x * 256 + threadIdx.x;  // 65536 = 16 b x 4096 n
  int b = g >> 12;
  int n = g & 4095;
  float s = 0.f;
#pragma unroll
  for (int sl = 0; sl < 16; ++sl) s += x2p[((size_t)(b * 16 + sl)) * NN + n];
  x2f[g] = s;
}

// ---------------- K1 v6: fused from bf16 tiles ----------------
// grid 1024 = 16 b x 64 chunks(64 n); 2 subs of 32 n. Staging = 8 coalesced
// 16B loads/thread from x_t (L3-warm). Phase 1/softmax/phase 2/epilogue
// identical to the verified r2 kernel. Sx2 from x2f (one 128B read).
#define XP2 36
__global__ __launch_bounds__(256, 4) void fused_kernel_v6(
    const unsigned short* __restrict__ xt, const float* __restrict__ x2f,
    const unsigned short* __restrict__ cwP, const float* __restrict__ c2g,
    const float* __restrict__ scale, float* __restrict__ partials,
    float* __restrict__ asum) {
  const int b = blockIdx.x >> 6;
  const int chunk = blockIdx.x & 63;
  const int t = threadIdx.x;
  const int w = t >> 6;
  const int l = t & 63;
  const int l15 = l & 15;
  const int q = l >> 4;
  const int wrole = (w + (blockIdx.x & 3)) & 3;

  __shared__ unsigned short Xl[CC * XP2];  // 36864 B
  __shared__ unsigned short As[KK * XP2];  // 2304 B
  __shared__ float Sx2[32];                // 128 B -> total 39296 B

  const float sc0 = scale[l15], sc1 = scale[16 + l15];
  const float cc0 = c2g[l15], cc1 = c2g[16 + l15];

  float4v acc[8][2];
#pragma unroll
  for (int ct = 0; ct < 8; ++ct)
#pragma unroll
    for (int m = 0; m < 2; ++m) acc[ct][m] = (float4v){0.f, 0.f, 0.f, 0.f};
  float s0acc = 0.f, s1acc = 0.f;

  for (int sub = 0; sub < 2; ++sub) {
    // ---- stage x_t tile -> Xl (8 x 16B coalesced loads per thread)
    const unsigned short* tile = xt + ((size_t)(blockIdx.x * 2 + sub)) * (CC * 32);
#pragma unroll
    for (int i = 0; i < 8; ++i) {
      const int idx = i * 256 + t;  // 16B unit; c = idx>>2, f = idx&3
      const int c = idx >> 2;
      const int f = idx & 3;
      uint4v v = *(const uint4v*)(tile + (size_t)idx * 8);
      *(uint2*)&Xl[c * XP2 + 8 * f] = make_uint2(v.x, v.y);
      *(uint2*)&Xl[c * XP2 + 8 * f + 4] = make_uint2(v.z, v.w);
    }
    __syncthreads();  // Xl visible

    // ---- phase 1 (waves wrole 0,1): xc via MFMA with permuted c-gather;
    //      wave wrole 2: load exact x2 for this sub's 32 n
    float4v p0 = (float4v){0.f, 0.f, 0.f, 0.f};
    float4v p1 = (float4v){0.f, 0.f, 0.f, 0.f};
    if (wrole < 2) {
      const int nrow = wrole * 16 + l15;
      for (int cs = 0; cs < 512; cs += 32) {
        const int cb2 = cs + 2 * q;
        short8 af;
#pragma unroll
        for (int j = 0; j < 8; ++j) {
          const int c = cb2 + (j & 1) + ((j >> 1) << 3);
          af[j] = (short)Xl[c * XP2 + nrow];
        }
        short8 b0 = *(const short8*)(cwP + (size_t)l15 * CC + cs + q * 8);
        short8 b1 = *(const short8*)(cwP + (size_t)(16 + l15) * CC + cs + q * 8);
        p0 = __builtin_amdgcn_mfma_f32_16x16x32_bf16(af, b0, p0, 0, 0, 0);
        p1 = __builtin_amdgcn_mfma_f32_16x16x32_bf16(af, b1, p1, 0, 0, 0);
      }
    } else if (wrole == 2 && l < 32) {
      Sx2[l] = x2f[b * NN + chunk * 64 + sub * 32 + l];
    }
    __syncthreads();  // Sx2 ready

    // ---- softmax per n (waves wrole 0,1): k spread over l15 lanes
    if (wrole < 2) {
      float a0[4], a1[4];
#pragma unroll
      for (int r = 0; r < 4; ++r) {
        const float xx = Sx2[wrole * 16 + 4 * q + r];
        float l0 = sc0 * (xx - 2.f * p0[r] + cc0);
        float l1 = sc1 * (xx - 2.f * p1[r] + cc1);
        float m = fmaxf(l0, l1);
        m = fmaxf(m, __shfl_xor(m, 1));
        m = fmaxf(m, __shfl_xor(m, 2));
        m = fmaxf(m, __shfl_xor(m, 4));
        m = fmaxf(m, __shfl_xor(m, 8));
        float e0 = __expf(l0 - m), e1 = __expf(l1 - m);
        float s = e0 + e1;
        s += __shfl_xor(s, 1);
        s += __shfl_xor(s, 2);
        s += __shfl_xor(s, 4);
        s += __shfl_xor(s, 8);
        float inv = 1.0f / s;
        a0[r] = e0 * inv;
        a1[r] = e1 * inv;
      }
      s0acc += a0[0] + a0[1] + a0[2] + a0[3];
      s1acc += a1[0] + a1[1] + a1[2] + a1[3];
      unsigned p00 = (unsigned)f2bf(a0[0]) | ((unsigned)f2bf(a0[1]) << 16);
      unsigned p01 = (unsigned)f2bf(a0[2]) | ((unsigned)f2bf(a0[3]) << 16);
      unsigned p10 = (unsigned)f2bf(a1[0]) | ((unsigned)f2bf(a1[1]) << 16);
      unsigned p11 = (unsigned)f2bf(a1[2]) | ((unsigned)f2bf(a1[3]) << 16);
      const int nc = wrole * 16 + 4 * q;
      *(uint2*)&As[l15 * XP2 + nc] = make_uint2(p00, p01);
      *(uint2*)&As[(16 + l15) * XP2 + nc] = make_uint2(p10, p11);
    }
    __syncthreads();  // As ready

    // ---- phase 2 (all waves): out_tile[k][c] += A . x^T over 32 n
    {
      const int nb = q * 8;
      const short4v* Ap0 = (const short4v*)&As[l15 * XP2 + nb];
      const short4v* Ap1 = (const short4v*)&As[(16 + l15) * XP2 + nb];
      short8 am0 = cat8(Ap0[0], Ap0[1]);
      short8 am1 = cat8(Ap1[0], Ap1[1]);
#pragma unroll
      for (int ct = 0; ct < 8; ++ct) {
        const int c = w * 128 + ct * 16 + l15;
        const short4v* Bp = (const short4v*)&Xl[c * XP2 + nb];
        short8 bx = cat8(Bp[0], Bp[1]);
        acc[ct][0] = __builtin_amdgcn_mfma_f32_16x16x32_bf16(am0, bx, acc[ct][0], 0, 0, 0);
        acc[ct][1] = __builtin_amdgcn_mfma_f32_16x16x32_bf16(am1, bx, acc[ct][1], 0, 0, 0);
      }
    }
    __syncthreads();  // protect Xl/As before next sub's staging
  }

  // ---- epilogue: streaming partial tile [32 k][512 c] for this block
  float* pout = partials + (size_t)blockIdx.x * KK * CC;
#pragma unroll
  for (int ct = 0; ct < 8; ++ct) {
    const int c = w * 128 + ct * 16 + l15;
#pragma unroll
    for (int m = 0; m < 2; ++m)
#pragma unroll
      for (int r = 0; r < 4; ++r) {
        int k = 16 * m + 4 * q + r;
        pout[k * CC + c] = acc[ct][m][r];
      }
  }
  // asum: only the phase-1 waves hold A-sums; reduce over q lanes
  s0acc += __shfl_xor(s0acc, 16);
  s0acc += __shfl_xor(s0acc, 32);
  s1acc += __shfl_xor(s1acc, 16);
  s1acc += __shfl_xor(s1acc, 32);
  if (wrole < 2 && q == 0) {
    atomicAdd(&asum[b * KK + l15], s0acc);
    atomicAdd(&asum[b * KK + 16 + l15], s1acc);
  }
}

// ---------------- legacy fused (r2-exact, fallback only) ----------------
template <int LOG2CH>
__global__ __launch_bounds__(256, 4) void fused_kernel_legacy(
    const float* __restrict__ x, const unsigned short* __restrict__ cwP,
    const float* __restrict__ c2g, const float* __restrict__ scale,
    float* __restrict__ partials, float* __restrict__ asum) {
  constexpr int CHN = NN >> LOG2CH;
  constexpr int SUBS = CHN / 32;
  const int b = blockIdx.x >> LOG2CH;
  const int chunk = blockIdx.x & ((1 << LOG2CH) - 1);
  const int t = threadIdx.x;
  const int w = t >> 6;
  const int l = t & 63;
  const int l15 = l & 15;
  const int q = l >> 4;
  const int wrole = (w + (blockIdx.x & 3)) & 3;

  __shared__ unsigned short Xl[CC * XP2];
  __shared__ unsigned short As[KK * XP2];
  __shared__ float Sx2w[4 * 32];
  __shared__ float Sx2[32];

  const float* xb0 = x + (size_t)b * CC * NN + chunk * CHN;
  const float sc0 = scale[l15], sc1 = scale[16 + l15];
  const float cc0 = c2g[l15], cc1 = c2g[16 + l15];

  float4v acc[8][2];
#pragma unroll
  for (int ct = 0; ct < 8; ++ct)
#pragma unroll
    for (int m = 0; m < 2; ++m) acc[ct][m] = (float4v){0.f, 0.f, 0.f, 0.f};
  float s0acc = 0.f, s1acc = 0.f;

  const int f4 = t & 7;
  const int cr = t >> 3;

  for (int sub = 0; sub < SUBS; ++sub) {
    const float* xb = xb0 + sub * 32;
    float4v x2p = (float4v){0.f, 0.f, 0.f, 0.f};
#pragma unroll 8
    for (int i = 0; i < 16; ++i) {
      const int c = cr + 32 * i;
      float4v v = *(const float4v*)(xb + (size_t)c * NN + 4 * f4);
      x2p.x = fmaf(v.x, v.x, x2p.x);
      x2p.y = fmaf(v.y, v.y, x2p.y);
      x2p.z = fmaf(v.z, v.z, x2p.z);
      x2p.w = fmaf(v.w, v.w, x2p.w);
      unsigned p0 = (unsigned)f2bf(v.x) | ((unsigned)f2bf(v.y) << 16);
      unsigned p1 = (unsigned)f2bf(v.z) | ((unsigned)f2bf(v.w) << 16);
      *(uint2*)&Xl[c * XP2 + 4 * f4] = make_uint2(p0, p1);
    }
#pragma unroll
    for (int m = 8; m <= 32; m <<= 1) {
      x2p.x += __shfl_xor(x2p.x, m);
      x2p.y += __shfl_xor(x2p.y, m);
      x2p.z += __shfl_xor(x2p.z, m);
      x2p.w += __shfl_xor(x2p.w, m);
    }
    if (l < 8) *(float4v*)&Sx2w[w * 32 + 4 * l] = x2p;
    __syncthreads();

    float4v p0 = (float4v){0.f, 0.f, 0.f, 0.f};
    float4v p1 = (float4v){0.f, 0.f, 0.f, 0.f};
    if (wrole < 2) {
      const int nrow = wrole * 16 + l15;
      for (int cs = 0; cs < 512; cs += 32) {
        const int cb2 = cs + 2 * q;
        short8 af;
#pragma unroll
        for (int j = 0; j < 8; ++j) {
          const int c = cb2 + (j & 1) + ((j >> 1) << 3);
          af[j] = (short)Xl[c * XP2 + nrow];
        }
        short8 b0 = *(const short8*)(cwP + (size_t)l15 * CC + cs + q * 8);
        short8 b1 = *(const short8*)(cwP + (size_t)(16 + l15) * CC + cs + q * 8);
        p0 = __builtin_amdgcn_mfma_f32_16x16x32_bf16(af, b0, p0, 0, 0, 0);
        p1 = __builtin_amdgcn_mfma_f32_16x16x32_bf16(af, b1, p1, 0, 0, 0);
      }
    } else if (wrole == 2 && l < 32) {
      Sx2[l] = Sx2w[l] + Sx2w[32 + l] + Sx2w[64 + l] + Sx2w[96 + l];
    }
    __syncthreads();

    if (wrole < 2) {
      float a0[4], a1[4];
#pragma unroll
      for (int r = 0; r < 4; ++r) {
        const float xx = Sx2[wrole * 16 + 4 * q + r];
        float l0 = sc0 * (xx - 2.f * p0[r] + cc0);
        float l1 = sc1 * (xx - 2.f * p1[r] + cc1);
        float m = fmaxf(l0, l1);
        m = fmaxf(m, __shfl_xor(m, 1));
        m = fmaxf(m, __shfl_xor(m, 2));
        m = fmaxf(m, __shfl_xor(m, 4));
        m = fmaxf(m, __shfl_xor(m, 8));
        float e0 = __expf(l0 - m), e1 = __expf(l1 - m);
        float s = e0 + e1;
        s += __shfl_xor(s, 1);
        s += __shfl_xor(s, 2);
        s += __shfl_xor(s, 4);
        s += __shfl_xor(s, 8);
        float inv = 1.0f / s;
        a0[r] = e0 * inv;
        a1[r] = e1 * inv;
      }
      s0acc += a0[0] + a0[1] + a0[2] + a0[3];
      s1acc += a1[0] + a1[1] + a1[2] + a1[3];
      unsigned p00 = (unsigned)f2bf(a0[0]) | ((unsigned)f2bf(a0[1]) << 16);
      unsigned p01 = (unsigned)f2bf(a0[2]) | ((unsigned)f2bf(a0[3]) << 16);
      unsigned p10 = (unsigned)f2bf(a1[0]) | ((unsigned)f2bf(a1[1]) << 16);
      unsigned p11 = (unsigned)f2bf(a1[2]) | ((unsigned)f2bf(a1[3]) << 16);
      const int nc = wrole * 16 + 4 * q;
      *(uint2*)&As[l15 * XP2 + nc] = make_uint2(p00, p01);
      *(uint2*)&As[(16 + l15) * XP2 + nc] = make_uint2(p10, p11);
    }
    __syncthreads();

    {
      const int nb = q * 8;
      const short4v* Ap0 = (const short4v*)&As[l15 * XP2 + nb];
      const short4v* Ap1 = (const short4v*)&As[(16 + l15) * XP2 + nb];
      short8 am0 = cat8(Ap0[0], Ap0[1]);
      short8 am1 = cat8(Ap1[0], Ap1[1]);
#pragma unroll
      for (int ct = 0; ct < 8; ++ct) {
        const int c = w * 128 + ct * 16 + l15;
        const short4v* Bp = (const short4v*)&Xl[c * XP2 + nb];
        short8 bx = cat8(Bp[0], Bp[1]);
        acc[ct][0] = __builtin_amdgcn_mfma_f32_16x16x32_bf16(am0, bx, acc[ct][0], 0, 0, 0);
        acc[ct][1] = __builtin_amdgcn_mfma_f32_16x16x32_bf16(am1, bx, acc[ct][1], 0, 0, 0);
      }
    }
    __syncthreads();
  }

  float* pout = partials + (size_t)blockIdx.x * KK * CC;
#pragma unroll
  for (int ct = 0; ct < 8; ++ct) {
    const int c = w * 128 + ct * 16 + l15;
#pragma unroll
    for (int m = 0; m < 2; ++m)
#pragma unroll
      for (int r = 0; r < 4; ++r) {
        int k = 16 * m + 4 * q + r;
        pout[k * CC + c] = acc[ct][m][r];
      }
  }
  s0acc += __shfl_xor(s0acc, 16);
  s0acc += __shfl_xor(s0acc, 32);
  s1acc += __shfl_xor(s1acc, 16);
  s1acc += __shfl_xor(s1acc, 32);
  if (wrole < 2 && q == 0) {
    atomicAdd(&asum[b * KK + l15], s0acc);
    atomicAdd(&asum[b * KK + 16 + l15], s1acc);
  }
}

// ---------------- K2: out = sum_chunk partials - asum * cw ----------------
template <int LOG2CH>
__global__ __launch_bounds__(256) void reduce_kernel(
    const float* __restrict__ partials, const float* __restrict__ asum,
    const float* __restrict__ cw, float* __restrict__ out) {
  constexpr int P = 1 << LOG2CH;
  int idx = blockIdx.x * 256 + threadIdx.x;  // float4 index, 65536 total
  int b = idx >> 12;
  int k = (idx >> 7) & 31;
  int c4 = idx & 127;

  float4v o = {0.f, 0.f, 0.f, 0.f};
  const float4v* pb =
      (const float4v*)partials + (((size_t)b << LOG2CH) * KK + k) * 128 + c4;
#pragma unroll 8
  for (int p = 0; p < P; ++p) {
    float4v v = pb[(size_t)p * KK * 128];
    o.x += v.x;
    o.y += v.y;
    o.z += v.z;
    o.w += v.w;
  }
  float4v wv = ((const float4v*)cw)[k * 128 + c4];
  float a = asum[b * KK + k];
  o.x -= a * wv.x;
  o.y -= a * wv.y;
  o.z -= a * wv.z;
  o.w -= a * wv.w;
  ((float4v*)out)[idx] = o;
}

extern "C" void kernel_launch(void* const* d_in, const int* in_sizes, int n_in,
                              void* d_out, int out_size, void* d_ws, size_t ws_size,
                              hipStream_t stream) {
  const float* x = (const float*)d_in[0];      // (16,512,64,64)
  const float* cw = (const float*)d_in[1];     // (32,512)
  const float* scale = (const float*)d_in[2];  // (32,)
  float* out = (float*)d_out;                  // (16,32,512)
  char* ws = (char*)d_ws;

  float* c2 = (float*)ws;                             // 128 B
  unsigned short* cwP = (unsigned short*)(ws + 128);  // 32 KB
  float* asum = (float*)(ws + 32896);                 // 2 KB

  constexpr size_t X2P_OFF = 35072;
  constexpr size_t X2P_SZ = (size_t)BB * 16 * NN * 4;          // 4 MB
  constexpr size_t X2F_OFF = X2P_OFF + X2P_SZ;
  constexpr size_t X2F_SZ = (size_t)BB * NN * 4;               // 256 KB
  constexpr size_t XT_OFF = X2F_OFF + X2F_SZ;
  constexpr size_t XT_SZ = (size_t)BB * 64 * 2 * CC * 32 * 2;  // 67 MB
  constexpr size_t PART_OFF = XT_OFF + XT_SZ;
  constexpr size_t PART_SZ = (size_t)1024 * KK * CC * 4;       // 64 MB
  constexpr size_t NEED = PART_OFF + PART_SZ;                  // ~138.7 MB

  prep_kernel<<<64, 256, 0, stream>>>(cw, cwP, c2, asum);

  if (ws_size >= NEED) {
    float* x2p = (float*)(ws + X2P_OFF);
    float* x2f = (float*)(ws + X2F_OFF);
    unsigned short* xt = (unsigned short*)(ws + XT_OFF);
    float* partials = (float*)(ws + PART_OFF);
    passA_kernel<<<256, 256, 0, stream>>>(x, xt, x2p);
    x2sum_kernel<<<256, 256, 0, stream>>>(x2p, x2f);
    fused_kernel_v6<<<1024, 256, 0, stream>>>(xt, x2f, cwP, c2, scale,
                                              partials, asum);
    reduce_kernel<6><<<256, 256, 0, stream>>>(partials, asum, cw, out);
  } else {
    // fallback: r2-exact single-pass path, grid 512, partials 32 MB
    float* partials = (float*)(ws + 35072);
    fused_kernel_legacy<5><<<512, 256, 0, stream>>>(x, cwP, c2, scale,
                                                    partials, asum);
    reduce_kernel<5><<<256, 256, 0, stream>>>(partials, asum, cw, out);
  }
}

// Round 6
// 231.411 us; speedup vs baseline: 1.1943x; 1.1943x over previous
//
#include <hip/hip_runtime.h>
#include <hip/hip_bf16.h>
#include <math.h>

// Problem: B=16, C=512, N=H*W=4096, K=32
#define BB 16
#define CC 512
#define NN 4096
#define KK 32

typedef __attribute__((ext_vector_type(8))) short short8;
typedef __attribute__((ext_vector_type(4))) short short4v;
typedef __attribute__((ext_vector_type(4))) float float4v;

static __device__ __forceinline__ unsigned short f2bf(float f) {
  unsigned u = __float_as_uint(f);
  u += 0x7FFF + ((u >> 16) & 1);  // RNE
  return (unsigned short)(u >> 16);
}

static __device__ __forceinline__ short8 cat8(short4v a, short4v b) {
  short8 r;
  r[0] = a[0]; r[1] = a[1]; r[2] = a[2]; r[3] = a[3];
  r[4] = b[0]; r[5] = b[1]; r[6] = b[2]; r[7] = b[3];
  return r;
}

// ws layout (bytes):
//   [0,128)        c2     (32 fp32)
//   [128,32896)    cwP    (32 k x 512 c) bf16, c-PERMUTED within 32-blocks
//   [32896,34944)  asum   (B*K fp32)
//   [35072,+64MB)  partials: 1024 x (32 k x 512 c) fp32
//   [+64MB,+72MB)  part2  : 8 grp x 65536 output-float4 fp32 (reduce stage 1)
//
// v7: fused reverted to the r2-exact kernel (best measured; r3 nt = write
// amplification, r4 reg-prefetch = scratch spills, r5 two-pass = flat fused
// + pass cost). New finding from r5 accounting: reduce was ~60-70us hidden
// below the top-5 cutoff — grid 256 = 1 block/CU (12% occupancy) reading
// 64 MB latency-exposed. Split into two occupancy-correct stages:
// reduce1 (grid 2048, 8 blk/CU, 8-way p-split -> part2) + reduce2 (fold 8,
// apply -asum*cw). Expected reduce path 60-70 -> ~15us.

// ---------------- K0: prep (unchanged) ----------------
__global__ __launch_bounds__(256) void prep_kernel(
    const float* __restrict__ cw, unsigned short* __restrict__ cwP,
    float* __restrict__ c2, float* __restrict__ asum) {
  int gid = blockIdx.x * 256 + threadIdx.x;  // 16384 threads = K*C
  if (gid < BB * KK) asum[gid] = 0.f;
  {
    int k = gid >> 9;
    int cc = gid & 511;
    int cs = cc & ~31;
    int w5 = cc & 31;
    int q = w5 >> 3, j = w5 & 7;
    int src_c = cs + 2 * q + (j & 1) + ((j >> 1) << 3);
    cwP[gid] = f2bf(cw[k * CC + src_c]);
  }
  __shared__ float c2p[KK][8];
  if (blockIdx.x == 0) {
    int k = threadIdx.x >> 3, j = threadIdx.x & 7;
    const float* row = cw + k * CC + j * 64;
    float s = 0.f;
    for (int i = 0; i < 64; ++i) s = fmaf(row[i], row[i], s);
    c2p[k][j] = s;
    __syncthreads();
    if (threadIdx.x < KK) {
      float t = 0.f;
      for (int j2 = 0; j2 < 8; ++j2) t += c2p[threadIdx.x][j2];
      c2[threadIdx.x] = t;
    }
  }
}

// ---------------- K1: fused (r2-exact) ----------------
//   LOG2CH=6: grid 1024, 64 n/chunk (2 subs)  -> 4 blocks/CU, 16 waves/CU
//   LOG2CH=5: grid 512, 128 n/chunk (4 subs)  -> fallback (small ws)
#define XP2 36
template <int LOG2CH>
__global__ __launch_bounds__(256, 4) void fused_kernel(
    const float* __restrict__ x, const unsigned short* __restrict__ cwP,
    const float* __restrict__ c2g, const float* __restrict__ scale,
    float* __restrict__ partials, float* __restrict__ asum) {
  constexpr int CHN = NN >> LOG2CH;  // n per chunk (64 or 128)
  constexpr int SUBS = CHN / 32;     // subs of 32 n (2 or 4)
  const int b = blockIdx.x >> LOG2CH;
  const int chunk = blockIdx.x & ((1 << LOG2CH) - 1);
  const int t = threadIdx.x;
  const int w = t >> 6;
  const int l = t & 63;
  const int l15 = l & 15;
  const int q = l >> 4;
  const int wrole = (w + (blockIdx.x & 3)) & 3;

  __shared__ unsigned short Xl[CC * XP2];  // 36864 B
  __shared__ unsigned short As[KK * XP2];  // 2304 B
  __shared__ float Sx2w[4 * 32];           // 512 B
  __shared__ float Sx2[32];                // 128 B -> total 39808 B

  const float* xb0 = x + (size_t)b * CC * NN + chunk * CHN;
  const float sc0 = scale[l15], sc1 = scale[16 + l15];
  const float cc0 = c2g[l15], cc1 = c2g[16 + l15];

  float4v acc[8][2];
#pragma unroll
  for (int ct = 0; ct < 8; ++ct)
#pragma unroll
    for (int m = 0; m < 2; ++m) acc[ct][m] = (float4v){0.f, 0.f, 0.f, 0.f};
  float s0acc = 0.f, s1acc = 0.f;

  const int f4 = t & 7;   // staging: n = 4*f4 .. 4*f4+3 (32 n per sub)
  const int cr = t >> 3;  // staging: c = cr + 32*i

  for (int sub = 0; sub < SUBS; ++sub) {
    const float* xb = xb0 + sub * 32;

    // ---- stage x -> Xl bf16; x2 partial per thread (16 c's)
    float4v x2p = (float4v){0.f, 0.f, 0.f, 0.f};
#pragma unroll 8
    for (int i = 0; i < 16; ++i) {
      const int c = cr + 32 * i;
      float4v v = *(const float4v*)(xb + (size_t)c * NN + 4 * f4);
      x2p.x = fmaf(v.x, v.x, x2p.x);
      x2p.y = fmaf(v.y, v.y, x2p.y);
      x2p.z = fmaf(v.z, v.z, x2p.z);
      x2p.w = fmaf(v.w, v.w, x2p.w);
      unsigned p0 = (unsigned)f2bf(v.x) | ((unsigned)f2bf(v.y) << 16);
      unsigned p1 = (unsigned)f2bf(v.z) | ((unsigned)f2bf(v.w) << 16);
      *(uint2*)&Xl[c * XP2 + 4 * f4] = make_uint2(p0, p1);
    }
    // in-wave reduce over the wave's 8 c-rows (lane bits 3,4,5)
#pragma unroll
    for (int m = 8; m <= 32; m <<= 1) {
      x2p.x += __shfl_xor(x2p.x, m);
      x2p.y += __shfl_xor(x2p.y, m);
      x2p.z += __shfl_xor(x2p.z, m);
      x2p.w += __shfl_xor(x2p.w, m);
    }
    if (l < 8) *(float4v*)&Sx2w[w * 32 + 4 * l] = x2p;
    __syncthreads();  // Xl + Sx2w visible

    // ---- phase 1 (waves wrole 0,1): xc via MFMA with permuted c-gather;
    //      wave wrole 2: finish x2 cross-wave sum
    float4v p0 = (float4v){0.f, 0.f, 0.f, 0.f};
    float4v p1 = (float4v){0.f, 0.f, 0.f, 0.f};
    if (wrole < 2) {
      const int nrow = wrole * 16 + l15;
      for (int cs = 0; cs < 512; cs += 32) {
        const int cb2 = cs + 2 * q;
        short8 af;
#pragma unroll
        for (int j = 0; j < 8; ++j) {
          const int c = cb2 + (j & 1) + ((j >> 1) << 3);
          af[j] = (short)Xl[c * XP2 + nrow];
        }
        short8 b0 = *(const short8*)(cwP + (size_t)l15 * CC + cs + q * 8);
        short8 b1 = *(const short8*)(cwP + (size_t)(16 + l15) * CC + cs + q * 8);
        p0 = __builtin_amdgcn_mfma_f32_16x16x32_bf16(af, b0, p0, 0, 0, 0);
        p1 = __builtin_amdgcn_mfma_f32_16x16x32_bf16(af, b1, p1, 0, 0, 0);
      }
    } else if (wrole == 2 && l < 32) {
      Sx2[l] = Sx2w[l] + Sx2w[32 + l] + Sx2w[64 + l] + Sx2w[96 + l];
    }
    __syncthreads();  // Sx2 ready

    // ---- softmax per n (waves wrole 0,1): k spread over l15 lanes
    if (wrole < 2) {
      float a0[4], a1[4];
#pragma unroll
      for (int r = 0; r < 4; ++r) {
        const float xx = Sx2[wrole * 16 + 4 * q + r];
        float l0 = sc0 * (xx - 2.f * p0[r] + cc0);
        float l1 = sc1 * (xx - 2.f * p1[r] + cc1);
        float m = fmaxf(l0, l1);
        m = fmaxf(m, __shfl_xor(m, 1));
        m = fmaxf(m, __shfl_xor(m, 2));
        m = fmaxf(m, __shfl_xor(m, 4));
        m = fmaxf(m, __shfl_xor(m, 8));
        float e0 = __expf(l0 - m), e1 = __expf(l1 - m);
        float s = e0 + e1;
        s += __shfl_xor(s, 1);
        s += __shfl_xor(s, 2);
        s += __shfl_xor(s, 4);
        s += __shfl_xor(s, 8);
        float inv = 1.0f / s;
        a0[r] = e0 * inv;
        a1[r] = e1 * inv;
      }
      s0acc += a0[0] + a0[1] + a0[2] + a0[3];
      s1acc += a1[0] + a1[1] + a1[2] + a1[3];
      unsigned p00 = (unsigned)f2bf(a0[0]) | ((unsigned)f2bf(a0[1]) << 16);
      unsigned p01 = (unsigned)f2bf(a0[2]) | ((unsigned)f2bf(a0[3]) << 16);
      unsigned p10 = (unsigned)f2bf(a1[0]) | ((unsigned)f2bf(a1[1]) << 16);
      unsigned p11 = (unsigned)f2bf(a1[2]) | ((unsigned)f2bf(a1[3]) << 16);
      const int nc = wrole * 16 + 4 * q;
      *(uint2*)&As[l15 * XP2 + nc] = make_uint2(p00, p01);
      *(uint2*)&As[(16 + l15) * XP2 + nc] = make_uint2(p10, p11);
    }
    __syncthreads();  // As ready

    // ---- phase 2 (all waves): out_tile[k][c] += A . x^T over 32 n
    {
      const int nb = q * 8;
      const short4v* Ap0 = (const short4v*)&As[l15 * XP2 + nb];
      const short4v* Ap1 = (const short4v*)&As[(16 + l15) * XP2 + nb];
      short8 am0 = cat8(Ap0[0], Ap0[1]);
      short8 am1 = cat8(Ap1[0], Ap1[1]);
#pragma unroll
      for (int ct = 0; ct < 8; ++ct) {
        const int c = w * 128 + ct * 16 + l15;
        const short4v* Bp = (const short4v*)&Xl[c * XP2 + nb];
        short8 bx = cat8(Bp[0], Bp[1]);
        acc[ct][0] = __builtin_amdgcn_mfma_f32_16x16x32_bf16(am0, bx, acc[ct][0], 0, 0, 0);
        acc[ct][1] = __builtin_amdgcn_mfma_f32_16x16x32_bf16(am1, bx, acc[ct][1], 0, 0, 0);
      }
    }
    __syncthreads();  // protect Xl/As before next sub's staging
  }

  // ---- epilogue: streaming partial tile [32 k][512 c] for this block
  float* pout = partials + (size_t)blockIdx.x * KK * CC;
#pragma unroll
  for (int ct = 0; ct < 8; ++ct) {
    const int c = w * 128 + ct * 16 + l15;
#pragma unroll
    for (int m = 0; m < 2; ++m)
#pragma unroll
      for (int r = 0; r < 4; ++r) {
        int k = 16 * m + 4 * q + r;
        pout[k * CC + c] = acc[ct][m][r];
      }
  }
  // asum: only the phase-1 waves hold A-sums; reduce over q lanes
  s0acc += __shfl_xor(s0acc, 16);
  s0acc += __shfl_xor(s0acc, 32);
  s1acc += __shfl_xor(s1acc, 16);
  s1acc += __shfl_xor(s1acc, 32);
  if (wrole < 2 && q == 0) {
    atomicAdd(&asum[b * KK + l15], s0acc);
    atomicAdd(&asum[b * KK + 16 + l15], s1acc);
  }
}

// ---------------- K2a: reduce stage 1 — 8-way p-split ----------------
// grid 2048 x 256 = 524288 threads = 8 grp x 65536 outputs.
// Each thread sums 8 of the 64 partial tiles for one output float4.
// 8 blocks/CU (vs old 1) -> latency hidden; reads coalesced (2KB runs).
__global__ __launch_bounds__(256) void reduce1_kernel(
    const float* __restrict__ partials, float* __restrict__ part2) {
  int gid = blockIdx.x * 256 + threadIdx.x;
  int o = gid & 65535;   // output float4 id: b(4) k(5) c4(7)
  int grp = gid >> 16;   // 0..7
  int b = o >> 12;
  int k = (o >> 7) & 31;
  int c4 = o & 127;

  const float4v* pb = (const float4v*)partials +
                      (((size_t)(b * 64 + grp * 8) * KK + k) * 128 + c4);
  float4v s = {0.f, 0.f, 0.f, 0.f};
#pragma unroll
  for (int p = 0; p < 8; ++p) {
    float4v v = pb[(size_t)p * KK * 128];
    s.x += v.x;
    s.y += v.y;
    s.z += v.z;
    s.w += v.w;
  }
  ((float4v*)part2)[(size_t)grp * 65536 + o] = s;
}

// ---------------- K2b: reduce stage 2 — fold 8 + epilogue ----------------
__global__ __launch_bounds__(256) void reduce2_kernel(
    const float* __restrict__ part2, const float* __restrict__ asum,
    const float* __restrict__ cw, float* __restrict__ out) {
  int o = blockIdx.x * 256 + threadIdx.x;  // 65536 outputs
  int b = o >> 12;
  int k = (o >> 7) & 31;
  int c4 = o & 127;

  float4v s = {0.f, 0.f, 0.f, 0.f};
#pragma unroll
  for (int grp = 0; grp < 8; ++grp) {
    float4v v = ((const float4v*)part2)[(size_t)grp * 65536 + o];
    s.x += v.x;
    s.y += v.y;
    s.z += v.z;
    s.w += v.w;
  }
  float4v wv = ((const float4v*)cw)[k * 128 + c4];
  float a = asum[b * KK + k];
  s.x -= a * wv.x;
  s.y -= a * wv.y;
  s.z -= a * wv.z;
  s.w -= a * wv.w;
  ((float4v*)out)[o] = s;
}

// ---------------- legacy single-stage reduce (fallback path) ------------
template <int LOG2CH>
__global__ __launch_bounds__(256) void reduce_kernel(
    const float* __restrict__ partials, const float* __restrict__ asum,
    const float* __restrict__ cw, float* __restrict__ out) {
  constexpr int P = 1 << LOG2CH;
  int idx = blockIdx.x * 256 + threadIdx.x;
  int b = idx >> 12;
  int k = (idx >> 7) & 31;
  int c4 = idx & 127;

  float4v o = {0.f, 0.f, 0.f, 0.f};
  const float4v* pb =
      (const float4v*)partials + (((size_t)b << LOG2CH) * KK + k) * 128 + c4;
#pragma unroll 8
  for (int p = 0; p < P; ++p) {
    float4v v = pb[(size_t)p * KK * 128];
    o.x += v.x;
    o.y += v.y;
    o.z += v.z;
    o.w += v.w;
  }
  float4v wv = ((const float4v*)cw)[k * 128 + c4];
  float a = asum[b * KK + k];
  o.x -= a * wv.x;
  o.y -= a * wv.y;
  o.z -= a * wv.z;
  o.w -= a * wv.w;
  ((float4v*)out)[idx] = o;
}

extern "C" void kernel_launch(void* const* d_in, const int* in_sizes, int n_in,
                              void* d_out, int out_size, void* d_ws, size_t ws_size,
                              hipStream_t stream) {
  const float* x = (const float*)d_in[0];      // (16,512,64,64)
  const float* cw = (const float*)d_in[1];     // (32,512)
  const float* scale = (const float*)d_in[2];  // (32,)
  float* out = (float*)d_out;                  // (16,32,512)
  char* ws = (char*)d_ws;

  float* c2 = (float*)ws;                             // 128 B
  unsigned short* cwP = (unsigned short*)(ws + 128);  // 32 KB
  float* asum = (float*)(ws + 32896);                 // 2 KB

  constexpr size_t PART_OFF = 35072;
  constexpr size_t PART_SZ = (size_t)1024 * KK * CC * 4;   // 64 MB
  constexpr size_t P2_OFF = PART_OFF + PART_SZ;
  constexpr size_t P2_SZ = (size_t)8 * 65536 * 16;         // 8 MB
  constexpr size_t NEED = P2_OFF + P2_SZ;                  // ~107 MB

  prep_kernel<<<64, 256, 0, stream>>>(cw, cwP, c2, asum);

  if (ws_size >= NEED) {
    float* partials = (float*)(ws + PART_OFF);
    float* part2 = (float*)(ws + P2_OFF);
    fused_kernel<6><<<1024, 256, 0, stream>>>(x, cwP, c2, scale, partials, asum);
    reduce1_kernel<<<2048, 256, 0, stream>>>(partials, part2);
    reduce2_kernel<<<256, 256, 0, stream>>>(part2, asum, cw, out);
  } else {
    // fallback: grid 512 configuration + single-stage reduce (known-good)
    float* partials = (float*)(ws + PART_OFF);
    fused_kernel<5><<<512, 256, 0, stream>>>(x, cwP, c2, scale, partials, asum);
    reduce_kernel<5><<<256, 256, 0, stream>>>(partials, asum, cw, out);
  }
}